// Round 1
// baseline (193.309 us; speedup 1.0000x reference)
//
#include <hip/hip_runtime.h>

// FeatureFuser: out = sigmoid(fused), fused[b,y,x] = refined[b,k,y,x] for the
// largest k whose rect contains (y,x), else sampling[b,y,x].
// Shapes: sampling (32,1,512,512) f32, refined (32,4,1,512,512) f32,
//         regions (32,4,2) int32. Rect = [r0*128, +384) x [r1*128, +384).
// Rect boundaries are multiples of 128 px (512 B) -> an aligned float4 never
// straddles a source boundary: one mask test per 4 pixels.
//
// This revision:
//  - b is derived from blockIdx.x (each block = 2048 contiguous px of one image)
//    so the 4 region int2 loads are wave-uniform -> s_load, rect math in SALU.
//  - 8 px/thread (two float4 chunks) halves per-pixel overhead.
//  - nontemporal store: out is never re-read; keep the 168 MB of inputs
//    L3-resident across timed iterations.

#define HH 512
#define WW 512
#define KTOP 4
#define GH 128
#define WIN 384
#define PX_PER_BLOCK 2048            // 256 threads * 8 px
#define TOTAL_PX (32 * HH * WW)      // 8,388,608

typedef float f32x4 __attribute__((ext_vector_type(4)));

__global__ __launch_bounds__(256) void featurefuser_kernel(
    const float* __restrict__ smap,      // (B,1,H,W)
    const float* __restrict__ rmaps,     // (B,K,1,H,W)
    const int*   __restrict__ regions,   // (B,K,2) int32
    float* __restrict__ out)             // (B,1,H,W)
{
    // 262144 px per image / 2048 px per block = 128 blocks per image
    const int b    = blockIdx.x >> 7;    // uniform across the block -> SGPR
    const int base = blockIdx.x << 11;   // first flat pixel of this block

    // Scalar rect computation: uniform addresses -> s_load_dwordx2 + SALU.
    int ry0[KTOP], ry1[KTOP], rx0[KTOP], rx1[KTOP];
#pragma unroll
    for (int k = 0; k < KTOP; ++k) {
        const int2 r = ((const int2*)regions)[b * KTOP + k];
        int y0 = r.x * GH; y0 = y0 < 0 ? 0 : (y0 > HH ? HH : y0);
        int x0 = r.y * GH; x0 = x0 < 0 ? 0 : (x0 > WW ? WW : x0);
        ry0[k] = y0; ry1[k] = (y0 + WIN > HH) ? HH : (y0 + WIN);
        rx0[k] = x0; rx1[k] = (x0 + WIN > WW) ? WW : (x0 + WIN);
    }

#pragma unroll
    for (int c = 0; c < 2; ++c) {
        const int idx   = base + (c << 10) + (threadIdx.x << 2); // flat pixel
        const int x     = idx & (WW - 1);
        const int y     = (idx >> 9) & (HH - 1);
        const int plane = idx & (HH * WW - 1);                   // y*W + x

        const float* src = smap + idx;
#pragma unroll
        for (int k = 0; k < KTOP; ++k) {
            const bool inside = (y >= ry0[k]) & (y < ry1[k]) &
                                (x >= rx0[k]) & (x < rx1[k]);
            const float* cand = rmaps + (((b * KTOP + k) << 18) + plane);
            src = inside ? cand : src;   // later k overrides (reference chain)
        }

        const float4 v = *(const float4*)src;
        f32x4 o;
        o.x = 1.0f / (1.0f + __expf(-v.x));
        o.y = 1.0f / (1.0f + __expf(-v.y));
        o.z = 1.0f / (1.0f + __expf(-v.z));
        o.w = 1.0f / (1.0f + __expf(-v.w));
        __builtin_nontemporal_store(o, (f32x4*)(out + idx));
    }
}

extern "C" void kernel_launch(void* const* d_in, const int* in_sizes, int n_in,
                              void* d_out, int out_size, void* d_ws, size_t ws_size,
                              hipStream_t stream) {
    const float* smap    = (const float*)d_in[0];
    const float* rmaps   = (const float*)d_in[1];
    const int*   regions = (const int*)d_in[2];
    float* out = (float*)d_out;

    const int grid = TOTAL_PX / PX_PER_BLOCK;   // 4096 blocks, 256 thr each
    featurefuser_kernel<<<grid, 256, 0, stream>>>(smap, rmaps, regions, out);
}